// Round 1
// 405.488 us; speedup vs baseline: 1.0071x; 1.0071x over previous
//
#include <hip/hip_runtime.h>
#include <hip/hip_bf16.h>

// Problem: B=8, H=W=128, C=F=256, 3x3 modulated conv (StyleGAN2 style).
// Strategy: bf16 MFMA implicit GEMM, async global_load_lds staging,
// double-buffered B, one barrier per tap, XCD-aware block swizzle.

#define NB 8
#define NH 128
#define NW 128
#define NC 256
#define NF 256

typedef __attribute__((ext_vector_type(8))) short bf16x8;
typedef __attribute__((ext_vector_type(4))) float f32x4;

// async 16B global -> LDS (dest = wave-uniform base + lane*16)
__device__ __forceinline__ void gload16(const ushort* g, ushort* l) {
    __builtin_amdgcn_global_load_lds(
        (const __attribute__((address_space(1))) unsigned int*)g,
        (__attribute__((address_space(3))) unsigned int*)l, 16, 0, 0);
}

// ---------------- x fp32 -> bf16 ----------------
__global__ void k_cvt(const float* __restrict__ x, ushort* __restrict__ xbf) {
    int i = (blockIdx.x * blockDim.x + threadIdx.x) * 4;
    float4 v = *(const float4*)(x + i);
    union { ushort4 u; __hip_bfloat16 h[4]; } o;
    o.h[0] = __float2bfloat16(v.x);
    o.h[1] = __float2bfloat16(v.y);
    o.h[2] = __float2bfloat16(v.z);
    o.h[3] = __float2bfloat16(v.w);
    *(ushort4*)(xbf + i) = o.u;
}

// ---------------- modulate + demodulate weights ----------------
// One block per (b,f), 256 threads (one per c). Writes wm layout [b][tap][f][c] bf16.
__global__ void k_modw(const float* __restrict__ kern, const float* __restrict__ style,
                       ushort* __restrict__ wm) {
    int b = blockIdx.x >> 8;
    int f = blockIdx.x & 255;
    int c = threadIdx.x;
    float s = style[b * 256 + c] + 1.0f;
    float w[9];
    float acc = 0.f;
#pragma unroll
    for (int t = 0; t < 9; ++t) {
        w[t] = kern[(t * 256 + c) * 256 + f] * s;
        acc += w[t] * w[t];
    }
#pragma unroll
    for (int off = 32; off; off >>= 1) acc += __shfl_down(acc, off);
    __shared__ float part[4];
    if ((threadIdx.x & 63) == 0) part[threadIdx.x >> 6] = acc;
    __syncthreads();
    float total = part[0] + part[1] + part[2] + part[3];
    float inv = 1.0f / sqrtf(total + 1e-8f);
#pragma unroll
    for (int t = 0; t < 9; ++t) {
        union { ushort u; __hip_bfloat16 h; } o;
        o.h = __float2bfloat16(w[t] * inv);
        wm[(((b * 9 + t) * 256 + f) * 256) + c] = o.u;
    }
}

// ---------------- conv as implicit GEMM ----------------
// Block = (b, h, f_half). M-tile = 128 (one image row), N-tile = 128 (half of F).
// K loop: 8 chunks of 32 c. Per chunk: A (3 rows + halo) staged once via
// global_load_lds; 9 taps with double-buffered B staged async one tap ahead.
// One __syncthreads per tap (its vmcnt drain IS the wait for the in-flight B).
__global__ void __launch_bounds__(256)
k_conv(const ushort* __restrict__ xbf, const ushort* __restrict__ wm,
       float* __restrict__ out) {
    // XCD swizzle: 2048 blocks = 8 XCDs * 256. Each XCD gets one sample b
    // -> wm[b] (1.18 MB) is XCD-L2 resident, x rows localize.
    const int bidx = (blockIdx.x & 7) * 256 + (blockIdx.x >> 3);
    const int fh = bidx & 1;
    const int h  = (bidx >> 1) & 127;
    const int b  = bidx >> 8;

    __shared__ ushort As[3][130 * 32];   // [dh][(w+1)*32 + c], w in [-1,128]
    __shared__ ushort Bs[2][128 * 32];   // double-buffered [f_local*32 + c]

    const int tid = threadIdx.x;
    const int wave = tid >> 6, lane = tid & 63;
    const int wm_ = wave & 1, wn_ = wave >> 1;   // 2x2 wave grid, each 64x64
    const int lrow = lane & 15;
    const int quad = lane >> 4;

    // staging lane geometry: lane covers row (lane>>2), c-part (lane&3)*8
    const int lw = lane >> 2;
    const int lc = (lane & 3) * 8;

    // Zero halo columns (w=-1 and w=128), constant across chunks.
    for (int i = tid; i < 3 * 2 * 32; i += 256) {
        int dh = i >> 6;
        int side = (i >> 5) & 1;
        int cc = i & 31;
        As[dh][(side ? 129 : 0) * 32 + cc] = 0;
    }
    // Zero out-of-image rows (constant across chunks; stages skip them).
#pragma unroll
    for (int dh = 0; dh < 3; ++dh) {
        int hp = h + dh - 1;
        if (hp < 0 || hp >= 128) {
            for (int i = tid; i < 130 * 32; i += 256) As[dh][i] = 0;
        }
    }

    f32x4 acc[4][4];
    const f32x4 zero4 = {0.f, 0.f, 0.f, 0.f};
#pragma unroll
    for (int mi = 0; mi < 4; ++mi)
#pragma unroll
        for (int ni = 0; ni < 4; ++ni) acc[mi][ni] = zero4;

    const ushort* wmb = wm + ((size_t)(b * 9) * 256 + fh * 128) * 256;

    // ---- async stagers (all-lane, block-uniform control flow) ----
    auto stageA = [&](int c0) {
#pragma unroll
        for (int dh = 0; dh < 3; ++dh) {
            int hp = h + dh - 1;
            if (hp >= 0 && hp < 128) {
                const ushort* src = xbf + ((size_t)(b * 128 + hp) * 128) * 256 + c0;
#pragma unroll
                for (int j = 0; j < 2; ++j) {
                    int w = j * 64 + wave * 16;      // wave-uniform base row
                    gload16(src + (w + lw) * 256 + lc, &As[dh][(w + 1) * 32]);
                }
            }
        }
    };
    auto stageB = [&](int tap, int buf, int c0) {
        const ushort* src = wmb + tap * 65536 + c0;
#pragma unroll
        for (int j = 0; j < 2; ++j) {
            int fl = j * 64 + wave * 16;
            gload16(src + (fl + lw) * 256 + lc, &Bs[buf][fl * 32]);
        }
    };

    // prologue: first chunk's A and tap-0 B in flight
    stageA(0);
    stageB(0, 0, 0);

    for (int ci = 0; ci < 8; ++ci) {
        const int c0 = ci * 32;
        __syncthreads();   // drains staged A(ci) + B(tap0); prev-chunk reads done
#pragma unroll
        for (int tap = 0; tap < 9; ++tap) {
            const int dh = tap / 3, dw = tap % 3;
            // issue next tap's B into the other buffer; it flies under this
            // tap's ds_reads + MFMAs and is drained by the trailing barrier.
            if (tap < 8) stageB(tap + 1, (tap + 1) & 1, c0);

            bf16x8 af[4], bfr[4];
#pragma unroll
            for (int ni = 0; ni < 4; ++ni) {
                int fl = wn_ * 64 + ni * 16 + lrow;
                bfr[ni] = *(const bf16x8*)&Bs[tap & 1][fl * 32 + quad * 8];
            }
#pragma unroll
            for (int mi = 0; mi < 4; ++mi) {
                int w = wm_ * 64 + mi * 16 + lrow;
                af[mi] = *(const bf16x8*)&As[dh][(w + dw) * 32 + quad * 8];
            }
#pragma unroll
            for (int mi = 0; mi < 4; ++mi)
#pragma unroll
                for (int ni = 0; ni < 4; ++ni)
                    acc[mi][ni] = __builtin_amdgcn_mfma_f32_16x16x32_bf16(
                        af[mi], bfr[ni], acc[mi][ni], 0, 0, 0);

            if (tap < 8) __syncthreads();  // waits vmcnt(0): B(tap+1) landed
        }
        if (ci < 7) {
            __syncthreads();               // tap-8 reads done before restaging
            stageA(c0 + 32);
            stageB(0, 0, c0 + 32);
        }
    }

    // ---- epilogue: C/D layout col=lane&15, row=quad*4+reg ----
    float* obase = out + ((size_t)(b * 128 + h) * 128) * 256 + fh * 128;
#pragma unroll
    for (int mi = 0; mi < 4; ++mi) {
        int wrow = wm_ * 64 + mi * 16 + quad * 4;
#pragma unroll
        for (int ni = 0; ni < 4; ++ni) {
            int f = wn_ * 64 + ni * 16 + lrow;
            f32x4 v = acc[mi][ni];
#pragma unroll
            for (int r = 0; r < 4; ++r) {
                obase[(wrow + r) * 256 + f] = v[r];
            }
        }
    }
}

extern "C" void kernel_launch(void* const* d_in, const int* in_sizes, int n_in,
                              void* d_out, int out_size, void* d_ws, size_t ws_size,
                              hipStream_t stream) {
    const float* x     = (const float*)d_in[0];   // [8,128,128,256]
    const float* style = (const float*)d_in[1];   // [8,1,1,256]
    const float* kern  = (const float*)d_in[2];   // [3,3,256,256]
    float* out = (float*)d_out;                   // [8,128,128,256]

    ushort* xbf = (ushort*)d_ws;                  // 33,554,432 bf16 = 64 MiB
    ushort* wmod = xbf + (size_t)NB * NH * NW * NC;  // 8*9*256*256 bf16 = 9 MiB

    k_cvt<<<(NB * NH * NW * NC) / (256 * 4), 256, 0, stream>>>(x, xbf);
    k_modw<<<NB * NF, 256, 0, stream>>>(kern, style, wmod);
    k_conv<<<NB * NH * 2, 256, 0, stream>>>(xbf, wmod, out);
}

// Round 2
// 373.805 us; speedup vs baseline: 1.0925x; 1.0848x over previous
//
#include <hip/hip_runtime.h>
#include <hip/hip_bf16.h>

// B=8, H=W=128, C=F=256, 3x3 modulated conv (StyleGAN2 style).
// bf16 MFMA implicit GEMM. Block = 128 rows x 256 F (full F), 4 waves of 64x128.
// LDS-read-bound fix: 0.375 reads/MFMA (was 0.5) + B-fragment prefetch pipeline
// (3 LDS B-buffers, stage 2 taps ahead, read frags 1 tap ahead, 1 barrier/tap).

#define NB 8
#define NH 128
#define NW 128
#define NC 256
#define NF 256

typedef __attribute__((ext_vector_type(8))) short bf16x8;
typedef __attribute__((ext_vector_type(4))) float f32x4;

// async 16B global -> LDS (dest = wave-uniform base + lane*16)
__device__ __forceinline__ void gload16(const ushort* g, ushort* l) {
    __builtin_amdgcn_global_load_lds(
        (const __attribute__((address_space(1))) unsigned int*)g,
        (__attribute__((address_space(3))) unsigned int*)l, 16, 0, 0);
}

// ---------------- x fp32 -> bf16 ----------------
__global__ void k_cvt(const float* __restrict__ x, ushort* __restrict__ xbf) {
    int i = (blockIdx.x * blockDim.x + threadIdx.x) * 4;
    float4 v = *(const float4*)(x + i);
    union { ushort4 u; __hip_bfloat16 h[4]; } o;
    o.h[0] = __float2bfloat16(v.x);
    o.h[1] = __float2bfloat16(v.y);
    o.h[2] = __float2bfloat16(v.z);
    o.h[3] = __float2bfloat16(v.w);
    *(ushort4*)(xbf + i) = o.u;
}

// ---------------- modulate + demodulate weights ----------------
// One block per (b,f), 256 threads (one per c). Writes wm layout [b][tap][f][c] bf16.
__global__ void k_modw(const float* __restrict__ kern, const float* __restrict__ style,
                       ushort* __restrict__ wm) {
    int b = blockIdx.x >> 8;
    int f = blockIdx.x & 255;
    int c = threadIdx.x;
    float s = style[b * 256 + c] + 1.0f;
    float w[9];
    float acc = 0.f;
#pragma unroll
    for (int t = 0; t < 9; ++t) {
        w[t] = kern[(t * 256 + c) * 256 + f] * s;
        acc += w[t] * w[t];
    }
#pragma unroll
    for (int off = 32; off; off >>= 1) acc += __shfl_down(acc, off);
    __shared__ float part[4];
    if ((threadIdx.x & 63) == 0) part[threadIdx.x >> 6] = acc;
    __syncthreads();
    float total = part[0] + part[1] + part[2] + part[3];
    float inv = 1.0f / sqrtf(total + 1e-8f);
#pragma unroll
    for (int t = 0; t < 9; ++t) {
        union { ushort u; __hip_bfloat16 h; } o;
        o.h = __float2bfloat16(w[t] * inv);
        wm[(((b * 9 + t) * 256 + f) * 256) + c] = o.u;
    }
}

// ---------------- conv as implicit GEMM ----------------
// Grid = B*H = 1024 blocks (XCD-swizzled: one sample b per XCD -> wm[b] L2-resident).
// Per block: M=128 (image row w), N=256 (all F). 4 waves, each 64x128 (acc[4][8]).
// K loop: 8 chunks of 32 c x 9 taps. Per tap: 4 A-frag reads (same tap) +
// 8 B-frag reads (NEXT tap, from 3-deep LDS pipeline) + 32 MFMA; 1 barrier.
__global__ void __launch_bounds__(256, 2)
k_conv(const ushort* __restrict__ xbf, const ushort* __restrict__ wm,
       float* __restrict__ out) {
    const int bidx = (blockIdx.x & 7) * 128 + (blockIdx.x >> 3);
    const int h = bidx & 127;
    const int b = bidx >> 7;

    __shared__ ushort As[3][130 * 32];   // [dh][(w+1)*32 + c], w in [-1,128]
    __shared__ ushort Bs[3][256 * 32];   // tap t lives in buffer t%3

    const int tid = threadIdx.x;
    const int wave = tid >> 6, lane = tid & 63;
    const int wm_ = wave & 1, wn_ = wave >> 1;   // wave tile: rows wm_*64, cols wn_*128
    const int lrow = lane & 15;
    const int quad = lane >> 4;
    const int lw = lane >> 2;          // staging: 16 rows per wave-load
    const int lc = (lane & 3) * 8;     // 4 x 16B per row

    // Zero halo columns (w=-1 and w=128), constant across chunks.
    for (int i = tid; i < 3 * 2 * 32; i += 256) {
        int dh = i >> 6;
        int side = (i >> 5) & 1;
        int cc = i & 31;
        As[dh][(side ? 129 : 0) * 32 + cc] = 0;
    }
    // Zero out-of-image rows once (stageA always skips them).
#pragma unroll
    for (int dh = 0; dh < 3; ++dh) {
        int hp = h + dh - 1;
        if (hp < 0 || hp >= 128) {
            for (int i = tid; i < 130 * 32; i += 256) As[dh][i] = 0;
        }
    }

    f32x4 acc[4][8];
    const f32x4 zero4 = {0.f, 0.f, 0.f, 0.f};
#pragma unroll
    for (int mi = 0; mi < 4; ++mi)
#pragma unroll
        for (int ni = 0; ni < 8; ++ni) acc[mi][ni] = zero4;

    const ushort* wmb = wm + (size_t)b * 9 * 65536;

    auto stageA = [&](int c0) {
#pragma unroll
        for (int dh = 0; dh < 3; ++dh) {
            int hp = h + dh - 1;
            if (hp >= 0 && hp < 128) {
                const ushort* src = xbf + ((size_t)(b * 128 + hp) * 128) * 256 + c0;
#pragma unroll
                for (int j = 0; j < 2; ++j) {
                    int w = j * 64 + wave * 16;      // wave-uniform base row
                    gload16(src + (w + lw) * 256 + lc, &As[dh][(w + 1) * 32]);
                }
            }
        }
    };
    auto stageB = [&](int c0, int tap, int buf) {
        const ushort* src = wmb + tap * 65536 + c0;
#pragma unroll
        for (int j = 0; j < 4; ++j) {
            int fl = j * 64 + wave * 16;
            gload16(src + (fl + lw) * 256 + lc, &Bs[buf][fl * 32]);
        }
    };

    bf16x8 af[4];
    bf16x8 bfr[2][8];   // fragment double-buffer: MFMA(t) uses bfr[t&1]

    // prologue: chunk0's A + taps 0,1 in flight
    stageA(0);
    stageB(0, 0, 0);
    stageB(0, 1, 1);

    for (int ci = 0; ci < 8; ++ci) {
        const int c0 = ci * 32;
        __syncthreads();   // drains all stages (A(ci), B taps 0/1); prev reads done
        // refill: tap0 B-fragments -> set 0
#pragma unroll
        for (int ni = 0; ni < 8; ++ni) {
            int fl = wn_ * 128 + ni * 16 + lrow;
            bfr[0][ni] = *(const bf16x8*)&Bs[0][fl * 32 + quad * 8];
        }
#pragma unroll
        for (int t = 0; t < 9; ++t) {
            if (t > 0) __syncthreads();          // buffer-recycle + visibility
            if (t < 7) stageB(c0, t + 2, (t + 2) % 3);   // 2 taps ahead
            const int dh = t / 3, dw = t % 3;
            // A frags for THIS tap (issued first so MFMA's lgkm wait is counted,
            // leaving the B-next reads in flight under the MFMA cluster)
#pragma unroll
            for (int mi = 0; mi < 4; ++mi) {
                int w = wm_ * 64 + mi * 16 + lrow;
                af[mi] = *(const bf16x8*)&As[dh][(w + dw) * 32 + quad * 8];
            }
            // B frags for NEXT tap
            if (t < 8) {
#pragma unroll
                for (int ni = 0; ni < 8; ++ni) {
                    int fl = wn_ * 128 + ni * 16 + lrow;
                    bfr[(t + 1) & 1][ni] =
                        *(const bf16x8*)&Bs[(t + 1) % 3][fl * 32 + quad * 8];
                }
            }
            // MFMA(t): af (this tap) x bfr[t&1] (prefetched last iter)
#pragma unroll
            for (int mi = 0; mi < 4; ++mi)
#pragma unroll
                for (int ni = 0; ni < 8; ++ni)
                    acc[mi][ni] = __builtin_amdgcn_mfma_f32_16x16x32_bf16(
                        af[mi], bfr[t & 1][ni], acc[mi][ni], 0, 0, 0);
        }
        __syncthreads();   // all reads of As(ci) and Bs done
        if (ci < 7) {
            stageA(c0 + 32);
            stageB(c0 + 32, 0, 0);
            stageB(c0 + 32, 1, 1);
        }
    }

    // ---- epilogue: C/D layout col=lane&15, row=quad*4+reg ----
    float* obase = out + ((size_t)(b * 128 + h) * 128) * 256;
#pragma unroll
    for (int mi = 0; mi < 4; ++mi) {
        int wrow = wm_ * 64 + mi * 16 + quad * 4;
#pragma unroll
        for (int ni = 0; ni < 8; ++ni) {
            int f = wn_ * 128 + ni * 16 + lrow;
            f32x4 v = acc[mi][ni];
#pragma unroll
            for (int r = 0; r < 4; ++r) {
                obase[(wrow + r) * 256 + f] = v[r];
            }
        }
    }
}

extern "C" void kernel_launch(void* const* d_in, const int* in_sizes, int n_in,
                              void* d_out, int out_size, void* d_ws, size_t ws_size,
                              hipStream_t stream) {
    const float* x     = (const float*)d_in[0];   // [8,128,128,256]
    const float* style = (const float*)d_in[1];   // [8,1,1,256]
    const float* kern  = (const float*)d_in[2];   // [3,3,256,256]
    float* out = (float*)d_out;                   // [8,128,128,256]

    ushort* xbf = (ushort*)d_ws;                  // 64 MiB
    ushort* wmod = xbf + (size_t)NB * NH * NW * NC;  // 9 MiB

    k_cvt<<<(NB * NH * NW * NC) / (256 * 4), 256, 0, stream>>>(x, xbf);
    k_modw<<<NB * NF, 256, 0, stream>>>(kern, style, wmod);
    k_conv<<<NB * NH, 256, 0, stream>>>(xbf, wmod, out);
}